// Round 2
// baseline (448.055 us; speedup 1.0000x reference)
//
#include <hip/hip_runtime.h>

#define DIM 128
#define HALF 64

typedef __attribute__((ext_vector_type(8))) short bf16x8;
typedef __attribute__((ext_vector_type(4))) float f32x4;

static __device__ __forceinline__ float bf2f(unsigned int u16) {
    unsigned int v = u16 << 16;
    return __builtin_bit_cast(float, v);
}
static __device__ __forceinline__ unsigned short f2bf(float f) {
    unsigned int u = __builtin_bit_cast(unsigned int, f);
    unsigned int r = 0x7fffu + ((u >> 16) & 1u);
    u += r;
    return (unsigned short)(u >> 16);
}

// ---------------- prep kernels ----------------

__global__ void conv_lower_kernel(const float* __restrict__ x,
                                  unsigned short* __restrict__ xl, int batch) {
    int i = blockIdx.x * 256 + threadIdx.x;
    if (i < batch * HALF) {
        int r = i >> 6, c = i & 63;
        xl[i] = f2bf(x[(size_t)r * DIM + c]);
    }
}

// w: [K][Nin] f32  ->  wt: [Npad][K] bf16 (transposed, optionally 23->24 group pad)
__global__ void transpose_w_kernel(const float* __restrict__ w,
                                   unsigned short* __restrict__ wt,
                                   int K, int Nin, int pad24) {
    __shared__ float tile[32][33];
    int bn = blockIdx.x, bk = blockIdx.y;
    int tx = threadIdx.x, ty = threadIdx.y;
#pragma unroll
    for (int i = 0; i < 4; ++i) {
        int k = bk * 32 + ty + 8 * i;
        int n = bn * 32 + tx;
        float v = 0.f;
        if (pad24) {
            int g = n / 24, cc = n % 24;
            if (cc < 23) v = w[(size_t)k * Nin + (g * 23 + cc)];
        } else {
            v = w[(size_t)k * Nin + n];
        }
        tile[ty + 8 * i][tx] = v;
    }
    __syncthreads();
#pragma unroll
    for (int i = 0; i < 4; ++i) {
        int n = bn * 32 + ty + 8 * i;
        int k = bk * 32 + tx;
        wt[(size_t)n * K + k] = f2bf(tile[tx][ty + 8 * i]);
    }
}

// ---------------- bf16 MFMA GEMM ----------------
// C[M][N] = act(A[M][K] @ B[K][N] + bias), A bf16, Bt = B^T bf16 [N][K], C bf16.
template <bool SILU, bool PAD24>
__global__ __launch_bounds__(256, 2) void gemm_bf16_kernel(
    const unsigned short* __restrict__ A, const unsigned short* __restrict__ Bt,
    const float* __restrict__ bias, unsigned short* __restrict__ C,
    int M, int N, int K) {
    constexpr int LDT = 72;  // 64 + 8 pad (bf16 elems) -> bank-spread rows
    __shared__ unsigned short a_lds[128 * LDT];
    __shared__ unsigned short b_lds[128 * LDT];

    const int t = threadIdx.x;
    const int lane = t & 63;
    const int wid = t >> 6;
    const int wr = wid >> 1, wc = wid & 1;
    const int m0 = blockIdx.x * 128;
    const int n0 = blockIdx.y * 128;
    const int l15 = lane & 15;
    const int l4 = lane >> 4;

    f32x4 acc[4][4] = {};

    const uint4* Ag = reinterpret_cast<const uint4*>(A + (size_t)m0 * K);
    const uint4* Bg = reinterpret_cast<const uint4*>(Bt + (size_t)n0 * K);
    const int krow = K >> 3;  // uint4 per full row

    for (int kt = 0; kt < K; kt += 64) {
        const int ktv = kt >> 3;
#pragma unroll
        for (int i = 0; i < 4; ++i) {
            int c = t + i * 256;
            int row = c >> 3, c8 = c & 7;
            uint4 av = Ag[(size_t)row * krow + ktv + c8];
            uint4 bv = Bg[(size_t)row * krow + ktv + c8];
            *reinterpret_cast<uint4*>(&a_lds[row * LDT + c8 * 8]) = av;
            *reinterpret_cast<uint4*>(&b_lds[row * LDT + c8 * 8]) = bv;
        }
        __syncthreads();
#pragma unroll
        for (int k0 = 0; k0 < 2; ++k0) {
            bf16x8 af[4], bf[4];
#pragma unroll
            for (int f = 0; f < 4; ++f) {
                af[f] = *reinterpret_cast<const bf16x8*>(
                    &a_lds[(wr * 64 + f * 16 + l15) * LDT + k0 * 32 + l4 * 8]);
                bf[f] = *reinterpret_cast<const bf16x8*>(
                    &b_lds[(wc * 64 + f * 16 + l15) * LDT + k0 * 32 + l4 * 8]);
            }
#pragma unroll
            for (int fm = 0; fm < 4; ++fm)
#pragma unroll
                for (int fn = 0; fn < 4; ++fn)
                    acc[fm][fn] = __builtin_amdgcn_mfma_f32_16x16x32_bf16(
                        af[fm], bf[fn], acc[fm][fn], 0, 0, 0);
        }
        __syncthreads();
    }

    // epilogue: bias (+silu) -> bf16
    float bv[4];
#pragma unroll
    for (int fn = 0; fn < 4; ++fn) {
        int n = n0 + wc * 64 + fn * 16 + l15;
        if (PAD24) {
            int g = n / 24, cc = n % 24;
            bv[fn] = (cc < 23) ? bias[g * 23 + cc] : 0.f;
        } else {
            bv[fn] = bias[n];
        }
    }
#pragma unroll
    for (int fm = 0; fm < 4; ++fm) {
#pragma unroll
        for (int r = 0; r < 4; ++r) {
            int row = m0 + wr * 64 + fm * 16 + l4 * 4 + r;
#pragma unroll
            for (int fn = 0; fn < 4; ++fn) {
                float v = acc[fm][fn][r] + bv[fn];
                if (SILU) v = v / (1.f + __expf(-v));
                C[(size_t)row * N + n0 + wc * 64 + fn * 16 + l15] = f2bf(v);
            }
        }
    }
}

// ---------------- RQS spline kernel ----------------
// One wave per batch row; lane = spline dim (64 dims).
// pass 1: transform upper half (xoff=64), write out fp32 + bf16 (fcnn2 input), ld1.
// pass 2: transform lower half (xoff=0), write out fp32, logdet = ld2+ld1.
__global__ void rqs_kernel(const float* __restrict__ x,
                           const unsigned short* __restrict__ P,  // [batch][1536]
                           float* __restrict__ out, unsigned short* __restrict__ out_bf,
                           float* __restrict__ ld_buf, float* __restrict__ logdet_out,
                           int xoff, int pass, int batch) {
    const int wid = threadIdx.x >> 6;
    const int lane = threadIdx.x & 63;
    const int r = blockIdx.x * 4 + wid;
    if (r >= batch) return;

    const uint4* pv = reinterpret_cast<const uint4*>(P + (size_t)r * 1536 + lane * 24);
    uint4 q0 = pv[0], q1 = pv[1], q2 = pv[2];

    float W[8], H[8], Dv[7];
    {
        unsigned int a;
        a = q0.x; W[0] = bf2f(a & 0xffff); W[1] = bf2f(a >> 16);
        a = q0.y; W[2] = bf2f(a & 0xffff); W[3] = bf2f(a >> 16);
        a = q0.z; W[4] = bf2f(a & 0xffff); W[5] = bf2f(a >> 16);
        a = q0.w; W[6] = bf2f(a & 0xffff); W[7] = bf2f(a >> 16);
        a = q1.x; H[0] = bf2f(a & 0xffff); H[1] = bf2f(a >> 16);
        a = q1.y; H[2] = bf2f(a & 0xffff); H[3] = bf2f(a >> 16);
        a = q1.z; H[4] = bf2f(a & 0xffff); H[5] = bf2f(a >> 16);
        a = q1.w; H[6] = bf2f(a & 0xffff); H[7] = bf2f(a >> 16);
        a = q2.x; Dv[0] = bf2f(a & 0xffff); Dv[1] = bf2f(a >> 16);
        a = q2.y; Dv[2] = bf2f(a & 0xffff); Dv[3] = bf2f(a >> 16);
        a = q2.z; Dv[4] = bf2f(a & 0xffff); Dv[5] = bf2f(a >> 16);
        a = q2.w; Dv[6] = bf2f(a & 0xffff);
    }

    // widths softmax -> cumw
    float cw[9], ch[9];
    {
        float m = W[0];
#pragma unroll
        for (int i = 1; i < 8; ++i) m = fmaxf(m, W[i]);
        float e[8], s = 0.f;
#pragma unroll
        for (int i = 0; i < 8; ++i) { e[i] = __expf(W[i] - m); s += e[i]; }
        float inv = 1.f / s, cum = 0.f;
        cw[0] = -1.f;
#pragma unroll
        for (int i = 0; i < 8; ++i) {
            cum += 0.001f + 0.992f * e[i] * inv;
            cw[i + 1] = 2.f * cum - 1.f;
        }
        cw[8] = 1.f;
    }
    {
        float m = H[0];
#pragma unroll
        for (int i = 1; i < 8; ++i) m = fmaxf(m, H[i]);
        float e[8], s = 0.f;
#pragma unroll
        for (int i = 0; i < 8; ++i) { e[i] = __expf(H[i] - m); s += e[i]; }
        float inv = 1.f / s, cum = 0.f;
        ch[0] = -1.f;
#pragma unroll
        for (int i = 0; i < 8; ++i) {
            cum += 0.001f + 0.992f * e[i] * inv;
            ch[i + 1] = 2.f * cum - 1.f;
        }
        ch[8] = 1.f;
    }
    float dv[9];
    dv[0] = 1.f; dv[8] = 1.f;
#pragma unroll
    for (int i = 0; i < 7; ++i) {
        float d = Dv[i];
        dv[i + 1] = 0.001f + fmaxf(d, 0.f) + log1pf(__expf(-fabsf(d)));
    }

    const float xv = x[(size_t)r * DIM + xoff + lane];

    int cnt = (xv >= -1.f) ? 1 : 0;
#pragma unroll
    for (int i = 1; i < 8; ++i) cnt += (xv >= cw[i]) ? 1 : 0;
    cnt += (xv >= 1.000001f) ? 1 : 0;
    int idx = cnt - 1;
    idx = idx < 0 ? 0 : (idx > 7 ? 7 : idx);

    float in_cumw = -1.f, in_w = 1.f, in_cumh = -1.f, in_h = 1.f, d0 = 1.f, d1 = 1.f;
#pragma unroll
    for (int i = 0; i < 8; ++i) {
        bool s = (idx == i);
        float wi = cw[i + 1] - cw[i];
        float hi = ch[i + 1] - ch[i];
        in_cumw = s ? cw[i] : in_cumw;
        in_w = s ? wi : in_w;
        in_cumh = s ? ch[i] : in_cumh;
        in_h = s ? hi : in_h;
        d0 = s ? dv[i] : d0;
        d1 = s ? dv[i + 1] : d1;
    }

    float in_delta = in_h / in_w;
    float theta = (xv - in_cumw) / in_w;
    float omt = 1.f - theta;
    float t1mt = theta * omt;
    float numer = in_h * (in_delta * theta * theta + d0 * t1mt);
    float denom = in_delta + (d0 + d1 - 2.f * in_delta) * t1mt;
    float outv = in_cumh + numer / denom;
    float dnum = in_delta * in_delta *
                 (d1 * theta * theta + 2.f * in_delta * t1mt + d0 * omt * omt);
    float lad = logf(dnum) - 2.f * logf(denom);

    bool inside = (xv >= -1.f) && (xv <= 1.f);
    outv = inside ? outv : xv;
    lad = inside ? lad : 0.f;

    out[(size_t)r * DIM + xoff + lane] = outv;
    if (pass == 1) out_bf[(size_t)r * HALF + lane] = f2bf(outv);

#pragma unroll
    for (int off = 32; off > 0; off >>= 1) lad += __shfl_xor(lad, off);

    if (lane == 0) {
        if (pass == 1) ld_buf[r] = lad;
        else logdet_out[r] = lad + ld_buf[r];
    }
}

// ---------------- launcher ----------------

extern "C" void kernel_launch(void* const* d_in, const int* in_sizes, int n_in,
                              void* d_out, int out_size, void* d_ws, size_t ws_size,
                              hipStream_t stream) {
    const float* x = (const float*)d_in[0];
    const float* f1w1 = (const float*)d_in[1];
    const float* f1b1 = (const float*)d_in[2];
    const float* f1w2 = (const float*)d_in[3];
    const float* f1b2 = (const float*)d_in[4];
    const float* f1w3 = (const float*)d_in[5];
    const float* f1b3 = (const float*)d_in[6];
    const float* f2w1 = (const float*)d_in[7];
    const float* f2b1 = (const float*)d_in[8];
    const float* f2w2 = (const float*)d_in[9];
    const float* f2b2 = (const float*)d_in[10];
    const float* f2w3 = (const float*)d_in[11];
    const float* f2b3 = (const float*)d_in[12];
    const int batch = in_sizes[0] / DIM;
    float* out = (float*)d_out;

    char* ws = (char*)d_ws;
    size_t off = 0;
    auto alloc = [&](size_t bytes) -> void* {
        void* p = ws + off;
        off += (bytes + 255) & ~(size_t)255;
        return p;
    };
    unsigned short* xl = (unsigned short*)alloc((size_t)batch * 64 * 2);
    unsigned short* ub = (unsigned short*)alloc((size_t)batch * 64 * 2);
    unsigned short* w1t1 = (unsigned short*)alloc(512 * 64 * 2);
    unsigned short* w2t1 = (unsigned short*)alloc(512 * 512 * 2);
    unsigned short* w3t1 = (unsigned short*)alloc(1536 * 512 * 2);
    unsigned short* w1t2 = (unsigned short*)alloc(512 * 64 * 2);
    unsigned short* w2t2 = (unsigned short*)alloc(512 * 512 * 2);
    unsigned short* w3t2 = (unsigned short*)alloc(1536 * 512 * 2);
    unsigned short* h1 = (unsigned short*)alloc((size_t)batch * 512 * 2);
    unsigned short* h2 = (unsigned short*)alloc((size_t)batch * 512 * 2);
    unsigned short* par = (unsigned short*)alloc((size_t)batch * 1536 * 2);
    float* ld1 = (float*)alloc((size_t)batch * 4);
    (void)ws_size; (void)n_in; (void)out_size;

    // prep
    conv_lower_kernel<<<(batch * 64 + 255) / 256, 256, 0, stream>>>(x, xl, batch);
    transpose_w_kernel<<<dim3(512 / 32, 64 / 32), dim3(32, 8), 0, stream>>>(f1w1, w1t1, 64, 512, 0);
    transpose_w_kernel<<<dim3(512 / 32, 512 / 32), dim3(32, 8), 0, stream>>>(f1w2, w2t1, 512, 512, 0);
    transpose_w_kernel<<<dim3(1536 / 32, 512 / 32), dim3(32, 8), 0, stream>>>(f1w3, w3t1, 512, 1472, 1);
    transpose_w_kernel<<<dim3(512 / 32, 64 / 32), dim3(32, 8), 0, stream>>>(f2w1, w1t2, 64, 512, 0);
    transpose_w_kernel<<<dim3(512 / 32, 512 / 32), dim3(32, 8), 0, stream>>>(f2w2, w2t2, 512, 512, 0);
    transpose_w_kernel<<<dim3(1536 / 32, 512 / 32), dim3(32, 8), 0, stream>>>(f2w3, w3t2, 512, 1472, 1);

    dim3 blk(256);
    // pass 1: fcnn(lower) -> transform upper
    gemm_bf16_kernel<true, false><<<dim3(batch / 128, 4), blk, 0, stream>>>(xl, w1t1, f1b1, h1, batch, 512, 64);
    gemm_bf16_kernel<true, false><<<dim3(batch / 128, 4), blk, 0, stream>>>(h1, w2t1, f1b2, h2, batch, 512, 512);
    gemm_bf16_kernel<false, true><<<dim3(batch / 128, 12), blk, 0, stream>>>(h2, w3t1, f1b3, par, batch, 1536, 512);
    rqs_kernel<<<batch / 4, 256, 0, stream>>>(x, par, out, ub, ld1, nullptr, HALF, 1, batch);
    // pass 2: fcnn(upper') -> transform lower
    gemm_bf16_kernel<true, false><<<dim3(batch / 128, 4), blk, 0, stream>>>(ub, w1t2, f2b1, h1, batch, 512, 64);
    gemm_bf16_kernel<true, false><<<dim3(batch / 128, 4), blk, 0, stream>>>(h1, w2t2, f2b2, h2, batch, 512, 512);
    gemm_bf16_kernel<false, true><<<dim3(batch / 128, 12), blk, 0, stream>>>(h2, w3t2, f2b3, par, batch, 1536, 512);
    rqs_kernel<<<batch / 4, 256, 0, stream>>>(x, par, out, nullptr, ld1, out + (size_t)batch * DIM, 0, 2, batch);
}

// Round 3
// 436.910 us; speedup vs baseline: 1.0255x; 1.0255x over previous
//
#include <hip/hip_runtime.h>

#define DIM 128
#define HALF 64

typedef __attribute__((ext_vector_type(8))) short bf16x8;
typedef __attribute__((ext_vector_type(4))) float f32x4;

static __device__ __forceinline__ float bf2f(unsigned int u16) {
    unsigned int v = u16 << 16;
    return __builtin_bit_cast(float, v);
}
static __device__ __forceinline__ unsigned short f2bf(float f) {
    unsigned int u = __builtin_bit_cast(unsigned int, f);
    unsigned int r = 0x7fffu + ((u >> 16) & 1u);
    u += r;
    return (unsigned short)(u >> 16);
}

// async global->LDS, 16B per lane; lds dest = wave-uniform base + lane*16
static __device__ __forceinline__ void gload_lds16(const void* gptr, void* ldsptr) {
    __builtin_amdgcn_global_load_lds(
        (const __attribute__((address_space(1))) unsigned int*)(uintptr_t)gptr,
        (__attribute__((address_space(3))) unsigned int*)(unsigned int)(uintptr_t)ldsptr,
        16, 0, 0);
}

// ---------------- prep kernels ----------------

__global__ void conv_lower_kernel(const float* __restrict__ x,
                                  unsigned short* __restrict__ xl, int batch) {
    int i = blockIdx.x * 256 + threadIdx.x;
    if (i < batch * HALF) {
        int r = i >> 6, c = i & 63;
        xl[i] = f2bf(x[(size_t)r * DIM + c]);
    }
}

struct TransDesc {
    const float* src[6];
    unsigned short* dst[6];
};

// all 6 weight transposes in one launch; z selects the matrix.
// w: [K][Nin] f32 -> wt: [Npad][K] bf16 (pad24: 23->24 group pad, Npad=1536)
__global__ void transpose_all_kernel(TransDesc d) {
    __shared__ float tile[32][33];
    int z = blockIdx.z;
    int K, BN, BK, Nin, pad24;
    switch (z) {
        case 0: case 3: K = 64;  BK = 2;  BN = 16; Nin = 512;  pad24 = 0; break;
        case 1: case 4: K = 512; BK = 16; BN = 16; Nin = 512;  pad24 = 0; break;
        default:        K = 512; BK = 16; BN = 48; Nin = 1472; pad24 = 1; break;
    }
    int bn = blockIdx.x, bk = blockIdx.y;
    if (bn >= BN || bk >= BK) return;
    const float* w = d.src[z];
    unsigned short* wt = d.dst[z];
    int tx = threadIdx.x, ty = threadIdx.y;
#pragma unroll
    for (int i = 0; i < 4; ++i) {
        int k = bk * 32 + ty + 8 * i;
        int n = bn * 32 + tx;
        float v = 0.f;
        if (pad24) {
            int g = n / 24, cc = n % 24;
            if (cc < 23) v = w[(size_t)k * Nin + (g * 23 + cc)];
        } else {
            v = w[(size_t)k * Nin + n];
        }
        tile[ty + 8 * i][tx] = v;
    }
    __syncthreads();
#pragma unroll
    for (int i = 0; i < 4; ++i) {
        int n = bn * 32 + ty + 8 * i;
        int k = bk * 32 + tx;
        wt[(size_t)n * K + k] = f2bf(tile[tx][ty + 8 * i]);
    }
}

// ---------------- bf16 MFMA GEMM (m97 structure) ----------------
// C[M][N] = act(A[M][K] @ B[K][N] + bias), A bf16, Bt = B^T bf16 [N][K], C bf16.
// 128x128 tile, BK=64, 4 waves, global_load_lds(16B) staging, linear LDS.
// 1-D grid with bijective XCD chunked swizzle; N-tile fastest so the NT blocks
// sharing one A panel are consecutive on one XCD (A fetched once chip-wide).
template <bool SILU, bool PAD24, int NT>
__global__ __launch_bounds__(256, 3) void gemm_bf16_kernel(
    const unsigned short* __restrict__ A, const unsigned short* __restrict__ Bt,
    const float* __restrict__ bias, unsigned short* __restrict__ C,
    int M, int N, int K) {
    __shared__ unsigned short a_lds[128 * 64];
    __shared__ unsigned short b_lds[128 * 64];

    const int t = threadIdx.x;
    const int lane = t & 63;
    const int wid = t >> 6;
    const int wr = wid >> 1, wc = wid & 1;

    const int nwg = gridDim.x;
    const int b = blockIdx.x;
    const int id = ((nwg & 7) == 0) ? ((b & 7) * (nwg >> 3) + (b >> 3)) : b;
    const int m0 = (id / NT) * 128;
    const int n0 = (id % NT) * 128;

    const int l15 = lane & 15;
    const int l4 = lane >> 4;
    const int srow = lane >> 3;   // staging: row within 8-row chunk
    const int sseg = lane & 7;    // staging: 16B segment within 128B row

    f32x4 acc[4][4] = {};

    for (int kt = 0; kt < K; kt += 64) {
#pragma unroll
        for (int i = 0; i < 4; ++i) {
            int chunk = wid * 4 + i;           // 8 rows per chunk
            int row = chunk * 8 + srow;
            const unsigned short* gA = A + (size_t)(m0 + row) * K + kt + sseg * 8;
            const unsigned short* gB = Bt + (size_t)(n0 + row) * K + kt + sseg * 8;
            gload_lds16(gA, &a_lds[chunk * 512]);
            gload_lds16(gB, &b_lds[chunk * 512]);
        }
        __syncthreads();
#pragma unroll
        for (int k0 = 0; k0 < 2; ++k0) {
            bf16x8 af[4], bfv[4];
#pragma unroll
            for (int f = 0; f < 4; ++f) {
                af[f] = *reinterpret_cast<const bf16x8*>(
                    &a_lds[(wr * 64 + f * 16 + l15) * 64 + k0 * 32 + l4 * 8]);
                bfv[f] = *reinterpret_cast<const bf16x8*>(
                    &b_lds[(wc * 64 + f * 16 + l15) * 64 + k0 * 32 + l4 * 8]);
            }
#pragma unroll
            for (int fm = 0; fm < 4; ++fm)
#pragma unroll
                for (int fn = 0; fn < 4; ++fn)
                    acc[fm][fn] = __builtin_amdgcn_mfma_f32_16x16x32_bf16(
                        af[fm], bfv[fn], acc[fm][fn], 0, 0, 0);
        }
        __syncthreads();
    }

    // epilogue: bias (+silu) -> bf16
    float bv[4];
#pragma unroll
    for (int fn = 0; fn < 4; ++fn) {
        int n = n0 + wc * 64 + fn * 16 + l15;
        if (PAD24) {
            int g = n / 24, cc = n % 24;
            bv[fn] = (cc < 23) ? bias[g * 23 + cc] : 0.f;
        } else {
            bv[fn] = bias[n];
        }
    }
#pragma unroll
    for (int fm = 0; fm < 4; ++fm) {
#pragma unroll
        for (int r = 0; r < 4; ++r) {
            int row = m0 + wr * 64 + fm * 16 + l4 * 4 + r;
#pragma unroll
            for (int fn = 0; fn < 4; ++fn) {
                float v = acc[fm][fn][r] + bv[fn];
                if (SILU) v = v / (1.f + __expf(-v));
                C[(size_t)row * N + n0 + wc * 64 + fn * 16 + l15] = f2bf(v);
            }
        }
    }
}

// ---------------- RQS spline kernel ----------------
// One wave per batch row; lane = spline dim (64 dims).
__global__ void rqs_kernel(const float* __restrict__ x,
                           const unsigned short* __restrict__ P,  // [batch][1536]
                           float* __restrict__ out, unsigned short* __restrict__ out_bf,
                           float* __restrict__ ld_buf, float* __restrict__ logdet_out,
                           int xoff, int pass, int batch) {
    const int wid = threadIdx.x >> 6;
    const int lane = threadIdx.x & 63;
    const int r = blockIdx.x * 4 + wid;
    if (r >= batch) return;

    const uint4* pv = reinterpret_cast<const uint4*>(P + (size_t)r * 1536 + lane * 24);
    uint4 q0 = pv[0], q1 = pv[1], q2 = pv[2];

    float W[8], H[8], Dv[7];
    {
        unsigned int a;
        a = q0.x; W[0] = bf2f(a & 0xffff); W[1] = bf2f(a >> 16);
        a = q0.y; W[2] = bf2f(a & 0xffff); W[3] = bf2f(a >> 16);
        a = q0.z; W[4] = bf2f(a & 0xffff); W[5] = bf2f(a >> 16);
        a = q0.w; W[6] = bf2f(a & 0xffff); W[7] = bf2f(a >> 16);
        a = q1.x; H[0] = bf2f(a & 0xffff); H[1] = bf2f(a >> 16);
        a = q1.y; H[2] = bf2f(a & 0xffff); H[3] = bf2f(a >> 16);
        a = q1.z; H[4] = bf2f(a & 0xffff); H[5] = bf2f(a >> 16);
        a = q1.w; H[6] = bf2f(a & 0xffff); H[7] = bf2f(a >> 16);
        a = q2.x; Dv[0] = bf2f(a & 0xffff); Dv[1] = bf2f(a >> 16);
        a = q2.y; Dv[2] = bf2f(a & 0xffff); Dv[3] = bf2f(a >> 16);
        a = q2.z; Dv[4] = bf2f(a & 0xffff); Dv[5] = bf2f(a >> 16);
        a = q2.w; Dv[6] = bf2f(a & 0xffff);
    }

    float cw[9], ch[9];
    {
        float m = W[0];
#pragma unroll
        for (int i = 1; i < 8; ++i) m = fmaxf(m, W[i]);
        float e[8], s = 0.f;
#pragma unroll
        for (int i = 0; i < 8; ++i) { e[i] = __expf(W[i] - m); s += e[i]; }
        float inv = 1.f / s, cum = 0.f;
        cw[0] = -1.f;
#pragma unroll
        for (int i = 0; i < 8; ++i) {
            cum += 0.001f + 0.992f * e[i] * inv;
            cw[i + 1] = 2.f * cum - 1.f;
        }
        cw[8] = 1.f;
    }
    {
        float m = H[0];
#pragma unroll
        for (int i = 1; i < 8; ++i) m = fmaxf(m, H[i]);
        float e[8], s = 0.f;
#pragma unroll
        for (int i = 0; i < 8; ++i) { e[i] = __expf(H[i] - m); s += e[i]; }
        float inv = 1.f / s, cum = 0.f;
        ch[0] = -1.f;
#pragma unroll
        for (int i = 0; i < 8; ++i) {
            cum += 0.001f + 0.992f * e[i] * inv;
            ch[i + 1] = 2.f * cum - 1.f;
        }
        ch[8] = 1.f;
    }
    float dv[9];
    dv[0] = 1.f; dv[8] = 1.f;
#pragma unroll
    for (int i = 0; i < 7; ++i) {
        float d = Dv[i];
        dv[i + 1] = 0.001f + fmaxf(d, 0.f) + log1pf(__expf(-fabsf(d)));
    }

    const float xv = x[(size_t)r * DIM + xoff + lane];

    int cnt = (xv >= -1.f) ? 1 : 0;
#pragma unroll
    for (int i = 1; i < 8; ++i) cnt += (xv >= cw[i]) ? 1 : 0;
    cnt += (xv >= 1.000001f) ? 1 : 0;
    int idx = cnt - 1;
    idx = idx < 0 ? 0 : (idx > 7 ? 7 : idx);

    float in_cumw = -1.f, in_w = 1.f, in_cumh = -1.f, in_h = 1.f, d0 = 1.f, d1 = 1.f;
#pragma unroll
    for (int i = 0; i < 8; ++i) {
        bool s = (idx == i);
        float wi = cw[i + 1] - cw[i];
        float hi = ch[i + 1] - ch[i];
        in_cumw = s ? cw[i] : in_cumw;
        in_w = s ? wi : in_w;
        in_cumh = s ? ch[i] : in_cumh;
        in_h = s ? hi : in_h;
        d0 = s ? dv[i] : d0;
        d1 = s ? dv[i + 1] : d1;
    }

    float in_delta = in_h / in_w;
    float theta = (xv - in_cumw) / in_w;
    float omt = 1.f - theta;
    float t1mt = theta * omt;
    float numer = in_h * (in_delta * theta * theta + d0 * t1mt);
    float denom = in_delta + (d0 + d1 - 2.f * in_delta) * t1mt;
    float outv = in_cumh + numer / denom;
    float dnum = in_delta * in_delta *
                 (d1 * theta * theta + 2.f * in_delta * t1mt + d0 * omt * omt);
    float lad = logf(dnum) - 2.f * logf(denom);

    bool inside = (xv >= -1.f) && (xv <= 1.f);
    outv = inside ? outv : xv;
    lad = inside ? lad : 0.f;

    out[(size_t)r * DIM + xoff + lane] = outv;
    if (pass == 1) out_bf[(size_t)r * HALF + lane] = f2bf(outv);

#pragma unroll
    for (int off = 32; off > 0; off >>= 1) lad += __shfl_xor(lad, off);

    if (lane == 0) {
        if (pass == 1) ld_buf[r] = lad;
        else logdet_out[r] = lad + ld_buf[r];
    }
}

// ---------------- launcher ----------------

extern "C" void kernel_launch(void* const* d_in, const int* in_sizes, int n_in,
                              void* d_out, int out_size, void* d_ws, size_t ws_size,
                              hipStream_t stream) {
    const float* x = (const float*)d_in[0];
    const float* f1w1 = (const float*)d_in[1];
    const float* f1b1 = (const float*)d_in[2];
    const float* f1w2 = (const float*)d_in[3];
    const float* f1b2 = (const float*)d_in[4];
    const float* f1w3 = (const float*)d_in[5];
    const float* f1b3 = (const float*)d_in[6];
    const float* f2w1 = (const float*)d_in[7];
    const float* f2b1 = (const float*)d_in[8];
    const float* f2w2 = (const float*)d_in[9];
    const float* f2b2 = (const float*)d_in[10];
    const float* f2w3 = (const float*)d_in[11];
    const float* f2b3 = (const float*)d_in[12];
    const int batch = in_sizes[0] / DIM;
    float* out = (float*)d_out;

    char* ws = (char*)d_ws;
    size_t off = 0;
    auto alloc = [&](size_t bytes) -> void* {
        void* p = ws + off;
        off += (bytes + 255) & ~(size_t)255;
        return p;
    };
    unsigned short* xl = (unsigned short*)alloc((size_t)batch * 64 * 2);
    unsigned short* ub = (unsigned short*)alloc((size_t)batch * 64 * 2);
    unsigned short* w1t1 = (unsigned short*)alloc(512 * 64 * 2);
    unsigned short* w2t1 = (unsigned short*)alloc(512 * 512 * 2);
    unsigned short* w3t1 = (unsigned short*)alloc(1536 * 512 * 2);
    unsigned short* w1t2 = (unsigned short*)alloc(512 * 64 * 2);
    unsigned short* w2t2 = (unsigned short*)alloc(512 * 512 * 2);
    unsigned short* w3t2 = (unsigned short*)alloc(1536 * 512 * 2);
    unsigned short* h1 = (unsigned short*)alloc((size_t)batch * 512 * 2);
    unsigned short* h2 = (unsigned short*)alloc((size_t)batch * 512 * 2);
    unsigned short* par = (unsigned short*)alloc((size_t)batch * 1536 * 2);
    float* ld1 = (float*)alloc((size_t)batch * 4);
    (void)ws_size; (void)n_in; (void)out_size;

    // prep
    conv_lower_kernel<<<(batch * 64 + 255) / 256, 256, 0, stream>>>(x, xl, batch);
    TransDesc td;
    td.src[0] = f1w1; td.dst[0] = w1t1;
    td.src[1] = f1w2; td.dst[1] = w2t1;
    td.src[2] = f1w3; td.dst[2] = w3t1;
    td.src[3] = f2w1; td.dst[3] = w1t2;
    td.src[4] = f2w2; td.dst[4] = w2t2;
    td.src[5] = f2w3; td.dst[5] = w3t2;
    transpose_all_kernel<<<dim3(48, 16, 6), dim3(32, 8), 0, stream>>>(td);

    dim3 blk(256);
    const int MB = batch / 128;
    // pass 1: fcnn(lower) -> transform upper
    gemm_bf16_kernel<true, false, 4><<<MB * 4, blk, 0, stream>>>(xl, w1t1, f1b1, h1, batch, 512, 64);
    gemm_bf16_kernel<true, false, 4><<<MB * 4, blk, 0, stream>>>(h1, w2t1, f1b2, h2, batch, 512, 512);
    gemm_bf16_kernel<false, true, 12><<<MB * 12, blk, 0, stream>>>(h2, w3t1, f1b3, par, batch, 1536, 512);
    rqs_kernel<<<batch / 4, 256, 0, stream>>>(x, par, out, ub, ld1, nullptr, HALF, 1, batch);
    // pass 2: fcnn(upper') -> transform lower
    gemm_bf16_kernel<true, false, 4><<<MB * 4, blk, 0, stream>>>(ub, w1t2, f2b1, h1, batch, 512, 64);
    gemm_bf16_kernel<true, false, 4><<<MB * 4, blk, 0, stream>>>(h1, w2t2, f2b2, h2, batch, 512, 512);
    gemm_bf16_kernel<false, true, 12><<<MB * 12, blk, 0, stream>>>(h2, w3t2, f2b3, par, batch, 1536, 512);
    rqs_kernel<<<batch / 4, 256, 0, stream>>>(x, par, out, nullptr, ld1, out + (size_t)batch * DIM, 0, 2, batch);
}

// Round 4
// 395.591 us; speedup vs baseline: 1.1326x; 1.1044x over previous
//
#include <hip/hip_runtime.h>

#define DIM 128
#define HALF 64

typedef __attribute__((ext_vector_type(8))) short bf16x8;
typedef __attribute__((ext_vector_type(4))) float f32x4;

static __device__ __forceinline__ float bf2f(unsigned int u16) {
    unsigned int v = u16 << 16;
    return __builtin_bit_cast(float, v);
}
static __device__ __forceinline__ unsigned short f2bf(float f) {
    unsigned int u = __builtin_bit_cast(unsigned int, f);
    unsigned int r = 0x7fffu + ((u >> 16) & 1u);
    u += r;
    return (unsigned short)(u >> 16);
}

// async global->LDS, 16B per lane; lds dest = wave-uniform base + lane*16
static __device__ __forceinline__ void gload_lds16(const void* gptr, void* ldsptr) {
    __builtin_amdgcn_global_load_lds(
        (const __attribute__((address_space(1))) unsigned int*)(uintptr_t)gptr,
        (__attribute__((address_space(3))) unsigned int*)(unsigned int)(uintptr_t)ldsptr,
        16, 0, 0);
}

// ---------------- prep kernels ----------------

__global__ void conv_lower_kernel(const float* __restrict__ x,
                                  unsigned short* __restrict__ xl, int batch) {
    int i = blockIdx.x * 256 + threadIdx.x;
    if (i < batch * HALF) {
        int r = i >> 6, c = i & 63;
        xl[i] = f2bf(x[(size_t)r * DIM + c]);
    }
}

struct TransDesc {
    const float* src[6];
    unsigned short* dst[6];
};

// all 6 weight transposes in one launch; z selects the matrix.
// w: [K][Nin] f32 -> wt: [Npad][K] bf16 (pad24: 23->24 group pad, Npad=1536)
__global__ void transpose_all_kernel(TransDesc d) {
    __shared__ float tile[32][33];
    int z = blockIdx.z;
    int K, BN, BK, Nin, pad24;
    switch (z) {
        case 0: case 3: K = 64;  BK = 2;  BN = 16; Nin = 512;  pad24 = 0; break;
        case 1: case 4: K = 512; BK = 16; BN = 16; Nin = 512;  pad24 = 0; break;
        default:        K = 512; BK = 16; BN = 48; Nin = 1472; pad24 = 1; break;
    }
    int bn = blockIdx.x, bk = blockIdx.y;
    if (bn >= BN || bk >= BK) return;
    const float* w = d.src[z];
    unsigned short* wt = d.dst[z];
    int tx = threadIdx.x, ty = threadIdx.y;
#pragma unroll
    for (int i = 0; i < 4; ++i) {
        int k = bk * 32 + ty + 8 * i;
        int n = bn * 32 + tx;
        float v = 0.f;
        if (pad24) {
            int g = n / 24, cc = n % 24;
            if (cc < 23) v = w[(size_t)k * Nin + (g * 23 + cc)];
        } else {
            v = w[(size_t)k * Nin + n];
        }
        tile[ty + 8 * i][tx] = v;
    }
    __syncthreads();
#pragma unroll
    for (int i = 0; i < 4; ++i) {
        int n = bn * 32 + ty + 8 * i;
        int k = bk * 32 + tx;
        wt[(size_t)n * K + k] = f2bf(tile[tx][ty + 8 * i]);
    }
}

// ---------------- bf16 MFMA GEMM (m97 structure + T2 swizzle rule#21) ----------------
// C[M][N] = act(A[M][K] @ B[K][N] + bias), A bf16, Bt = B^T bf16 [N][K], C bf16.
// 128x128 tile, BK=64, 4 waves, global_load_lds(16B) staging (linear LDS dest,
// pre-swizzled GLOBAL source), XOR-swizzled ds_read -> all 32 banks hit.
// XCD chunked swizzle, N-tile fastest (A panel fetched once chip-wide).
template <bool SILU, bool PAD24, int NT>
__global__ __launch_bounds__(256, 4) void gemm_bf16_kernel(
    const unsigned short* __restrict__ A, const unsigned short* __restrict__ Bt,
    const float* __restrict__ bias, unsigned short* __restrict__ C,
    int M, int N, int K) {
    __shared__ __align__(16) unsigned char smem[34816];
    unsigned short* a_lds = (unsigned short*)smem;            // [128][64] linear
    unsigned short* b_lds = (unsigned short*)(smem + 16384);  // [128][64] linear
    unsigned short* cbuf = (unsigned short*)smem;             // epilogue, stride 136

    const int t = threadIdx.x;
    const int lane = t & 63;
    const int wid = t >> 6;
    const int wr = wid >> 1, wc = wid & 1;

    const int nwg = gridDim.x;
    const int b = blockIdx.x;
    const int id = ((nwg & 7) == 0) ? ((b & 7) * (nwg >> 3) + (b >> 3)) : b;
    const int m0 = (id / NT) * 128;
    const int n0 = (id % NT) * 128;

    const int l15 = lane & 15;
    const int l4 = lane >> 4;
    const int srow = lane >> 3;   // staging: row within 8-row chunk (0..7)
    const int sseg = lane & 7;    // staging: 16B segment within 128B row (0..7)
    const int sseg_swz = sseg ^ srow;   // pre-swizzled global segment
    const int rswz = (l15 & 7) * 8;     // ds_read elem-XOR for this lane's rows

    f32x4 acc[4][4] = {};

    for (int kt = 0; kt < K; kt += 64) {
#pragma unroll
        for (int i = 0; i < 4; ++i) {
            int chunk = wid * 4 + i;           // 8 rows per chunk
            int row = chunk * 8 + srow;
            const unsigned short* gA = A + (size_t)(m0 + row) * K + kt + sseg_swz * 8;
            const unsigned short* gB = Bt + (size_t)(n0 + row) * K + kt + sseg_swz * 8;
            gload_lds16(gA, &a_lds[chunk * 512]);
            gload_lds16(gB, &b_lds[chunk * 512]);
        }
        __syncthreads();
#pragma unroll
        for (int k0 = 0; k0 < 2; ++k0) {
            bf16x8 af[4], bfv[4];
#pragma unroll
            for (int f = 0; f < 4; ++f) {
                int col = (k0 * 32 + l4 * 8) ^ rswz;
                af[f] = *reinterpret_cast<const bf16x8*>(
                    &a_lds[(wr * 64 + f * 16 + l15) * 64 + col]);
                bfv[f] = *reinterpret_cast<const bf16x8*>(
                    &b_lds[(wc * 64 + f * 16 + l15) * 64 + col]);
            }
#pragma unroll
            for (int fm = 0; fm < 4; ++fm)
#pragma unroll
                for (int fn = 0; fn < 4; ++fn)
                    acc[fm][fn] = __builtin_amdgcn_mfma_f32_16x16x32_bf16(
                        af[fm], bfv[fn], acc[fm][fn], 0, 0, 0);
        }
        __syncthreads();
    }

    // epilogue: bias (+silu) -> bf16 tile in LDS (stride 136) -> coalesced 16B stores
    float bv[4];
#pragma unroll
    for (int fn = 0; fn < 4; ++fn) {
        int n = n0 + wc * 64 + fn * 16 + l15;
        if (PAD24) {
            int g = n / 24, cc = n % 24;
            bv[fn] = (cc < 23) ? bias[g * 23 + cc] : 0.f;
        } else {
            bv[fn] = bias[n];
        }
    }
#pragma unroll
    for (int fm = 0; fm < 4; ++fm) {
#pragma unroll
        for (int r = 0; r < 4; ++r) {
            int rl = wr * 64 + fm * 16 + l4 * 4 + r;
#pragma unroll
            for (int fn = 0; fn < 4; ++fn) {
                float v = acc[fm][fn][r] + bv[fn];
                if (SILU) v = v / (1.f + __expf(-v));
                cbuf[rl * 136 + wc * 64 + fn * 16 + l15] = f2bf(v);
            }
        }
    }
    __syncthreads();
#pragma unroll
    for (int p = 0; p < 8; ++p) {
        int unit = p * 256 + t;       // 2048 units = 128 rows x 16 segs
        int row = unit >> 4, seg = unit & 15;
        uint4 v = *reinterpret_cast<const uint4*>(&cbuf[row * 136 + seg * 8]);
        *reinterpret_cast<uint4*>(&C[(size_t)(m0 + row) * N + n0 + seg * 8]) = v;
    }
}

// ---------------- RQS spline kernel ----------------
// One wave per batch row; lane = spline dim (64 dims).
__global__ void rqs_kernel(const float* __restrict__ x,
                           const unsigned short* __restrict__ P,  // [batch][1536]
                           float* __restrict__ out, unsigned short* __restrict__ out_bf,
                           float* __restrict__ ld_buf, float* __restrict__ logdet_out,
                           int xoff, int pass, int batch) {
    const int wid = threadIdx.x >> 6;
    const int lane = threadIdx.x & 63;
    const int r = blockIdx.x * 4 + wid;
    if (r >= batch) return;

    const uint4* pv = reinterpret_cast<const uint4*>(P + (size_t)r * 1536 + lane * 24);
    uint4 q0 = pv[0], q1 = pv[1], q2 = pv[2];

    float W[8], H[8], Dv[7];
    {
        unsigned int a;
        a = q0.x; W[0] = bf2f(a & 0xffff); W[1] = bf2f(a >> 16);
        a = q0.y; W[2] = bf2f(a & 0xffff); W[3] = bf2f(a >> 16);
        a = q0.z; W[4] = bf2f(a & 0xffff); W[5] = bf2f(a >> 16);
        a = q0.w; W[6] = bf2f(a & 0xffff); W[7] = bf2f(a >> 16);
        a = q1.x; H[0] = bf2f(a & 0xffff); H[1] = bf2f(a >> 16);
        a = q1.y; H[2] = bf2f(a & 0xffff); H[3] = bf2f(a >> 16);
        a = q1.z; H[4] = bf2f(a & 0xffff); H[5] = bf2f(a >> 16);
        a = q1.w; H[6] = bf2f(a & 0xffff); H[7] = bf2f(a >> 16);
        a = q2.x; Dv[0] = bf2f(a & 0xffff); Dv[1] = bf2f(a >> 16);
        a = q2.y; Dv[2] = bf2f(a & 0xffff); Dv[3] = bf2f(a >> 16);
        a = q2.z; Dv[4] = bf2f(a & 0xffff); Dv[5] = bf2f(a >> 16);
        a = q2.w; Dv[6] = bf2f(a & 0xffff);
    }

    float cw[9], ch[9];
    {
        float m = W[0];
#pragma unroll
        for (int i = 1; i < 8; ++i) m = fmaxf(m, W[i]);
        float e[8], s = 0.f;
#pragma unroll
        for (int i = 0; i < 8; ++i) { e[i] = __expf(W[i] - m); s += e[i]; }
        float inv = 1.f / s, cum = 0.f;
        cw[0] = -1.f;
#pragma unroll
        for (int i = 0; i < 8; ++i) {
            cum += 0.001f + 0.992f * e[i] * inv;
            cw[i + 1] = 2.f * cum - 1.f;
        }
        cw[8] = 1.f;
    }
    {
        float m = H[0];
#pragma unroll
        for (int i = 1; i < 8; ++i) m = fmaxf(m, H[i]);
        float e[8], s = 0.f;
#pragma unroll
        for (int i = 0; i < 8; ++i) { e[i] = __expf(H[i] - m); s += e[i]; }
        float inv = 1.f / s, cum = 0.f;
        ch[0] = -1.f;
#pragma unroll
        for (int i = 0; i < 8; ++i) {
            cum += 0.001f + 0.992f * e[i] * inv;
            ch[i + 1] = 2.f * cum - 1.f;
        }
        ch[8] = 1.f;
    }
    float dv[9];
    dv[0] = 1.f; dv[8] = 1.f;
#pragma unroll
    for (int i = 0; i < 7; ++i) {
        float d = Dv[i];
        dv[i + 1] = 0.001f + fmaxf(d, 0.f) + log1pf(__expf(-fabsf(d)));
    }

    const float xv = x[(size_t)r * DIM + xoff + lane];

    int cnt = (xv >= -1.f) ? 1 : 0;
#pragma unroll
    for (int i = 1; i < 8; ++i) cnt += (xv >= cw[i]) ? 1 : 0;
    cnt += (xv >= 1.000001f) ? 1 : 0;
    int idx = cnt - 1;
    idx = idx < 0 ? 0 : (idx > 7 ? 7 : idx);

    float in_cumw = -1.f, in_w = 1.f, in_cumh = -1.f, in_h = 1.f, d0 = 1.f, d1 = 1.f;
#pragma unroll
    for (int i = 0; i < 8; ++i) {
        bool s = (idx == i);
        float wi = cw[i + 1] - cw[i];
        float hi = ch[i + 1] - ch[i];
        in_cumw = s ? cw[i] : in_cumw;
        in_w = s ? wi : in_w;
        in_cumh = s ? ch[i] : in_cumh;
        in_h = s ? hi : in_h;
        d0 = s ? dv[i] : d0;
        d1 = s ? dv[i + 1] : d1;
    }

    float in_delta = in_h / in_w;
    float theta = (xv - in_cumw) / in_w;
    float omt = 1.f - theta;
    float t1mt = theta * omt;
    float numer = in_h * (in_delta * theta * theta + d0 * t1mt);
    float denom = in_delta + (d0 + d1 - 2.f * in_delta) * t1mt;
    float outv = in_cumh + numer / denom;
    float dnum = in_delta * in_delta *
                 (d1 * theta * theta + 2.f * in_delta * t1mt + d0 * omt * omt);
    float lad = logf(dnum) - 2.f * logf(denom);

    bool inside = (xv >= -1.f) && (xv <= 1.f);
    outv = inside ? outv : xv;
    lad = inside ? lad : 0.f;

    out[(size_t)r * DIM + xoff + lane] = outv;
    if (pass == 1) out_bf[(size_t)r * HALF + lane] = f2bf(outv);

#pragma unroll
    for (int off = 32; off > 0; off >>= 1) lad += __shfl_xor(lad, off);

    if (lane == 0) {
        if (pass == 1) ld_buf[r] = lad;
        else logdet_out[r] = lad + ld_buf[r];
    }
}

// ---------------- launcher ----------------

extern "C" void kernel_launch(void* const* d_in, const int* in_sizes, int n_in,
                              void* d_out, int out_size, void* d_ws, size_t ws_size,
                              hipStream_t stream) {
    const float* x = (const float*)d_in[0];
    const float* f1w1 = (const float*)d_in[1];
    const float* f1b1 = (const float*)d_in[2];
    const float* f1w2 = (const float*)d_in[3];
    const float* f1b2 = (const float*)d_in[4];
    const float* f1w3 = (const float*)d_in[5];
    const float* f1b3 = (const float*)d_in[6];
    const float* f2w1 = (const float*)d_in[7];
    const float* f2b1 = (const float*)d_in[8];
    const float* f2w2 = (const float*)d_in[9];
    const float* f2b2 = (const float*)d_in[10];
    const float* f2w3 = (const float*)d_in[11];
    const float* f2b3 = (const float*)d_in[12];
    const int batch = in_sizes[0] / DIM;
    float* out = (float*)d_out;

    char* ws = (char*)d_ws;
    size_t off = 0;
    auto alloc = [&](size_t bytes) -> void* {
        void* p = ws + off;
        off += (bytes + 255) & ~(size_t)255;
        return p;
    };
    unsigned short* xl = (unsigned short*)alloc((size_t)batch * 64 * 2);
    unsigned short* ub = (unsigned short*)alloc((size_t)batch * 64 * 2);
    unsigned short* w1t1 = (unsigned short*)alloc(512 * 64 * 2);
    unsigned short* w2t1 = (unsigned short*)alloc(512 * 512 * 2);
    unsigned short* w3t1 = (unsigned short*)alloc(1536 * 512 * 2);
    unsigned short* w1t2 = (unsigned short*)alloc(512 * 64 * 2);
    unsigned short* w2t2 = (unsigned short*)alloc(512 * 512 * 2);
    unsigned short* w3t2 = (unsigned short*)alloc(1536 * 512 * 2);
    unsigned short* h1 = (unsigned short*)alloc((size_t)batch * 512 * 2);
    unsigned short* h2 = (unsigned short*)alloc((size_t)batch * 512 * 2);
    unsigned short* par = (unsigned short*)alloc((size_t)batch * 1536 * 2);
    float* ld1 = (float*)alloc((size_t)batch * 4);
    (void)ws_size; (void)n_in; (void)out_size;

    // prep
    conv_lower_kernel<<<(batch * 64 + 255) / 256, 256, 0, stream>>>(x, xl, batch);
    TransDesc td;
    td.src[0] = f1w1; td.dst[0] = w1t1;
    td.src[1] = f1w2; td.dst[1] = w2t1;
    td.src[2] = f1w3; td.dst[2] = w3t1;
    td.src[3] = f2w1; td.dst[3] = w1t2;
    td.src[4] = f2w2; td.dst[4] = w2t2;
    td.src[5] = f2w3; td.dst[5] = w3t2;
    transpose_all_kernel<<<dim3(48, 16, 6), dim3(32, 8), 0, stream>>>(td);

    dim3 blk(256);
    const int MB = batch / 128;
    // pass 1: fcnn(lower) -> transform upper
    gemm_bf16_kernel<true, false, 4><<<MB * 4, blk, 0, stream>>>(xl, w1t1, f1b1, h1, batch, 512, 64);
    gemm_bf16_kernel<true, false, 4><<<MB * 4, blk, 0, stream>>>(h1, w2t1, f1b2, h2, batch, 512, 512);
    gemm_bf16_kernel<false, true, 12><<<MB * 12, blk, 0, stream>>>(h2, w3t1, f1b3, par, batch, 1536, 512);
    rqs_kernel<<<batch / 4, 256, 0, stream>>>(x, par, out, ub, ld1, nullptr, HALF, 1, batch);
    // pass 2: fcnn(upper') -> transform lower
    gemm_bf16_kernel<true, false, 4><<<MB * 4, blk, 0, stream>>>(ub, w1t2, f2b1, h1, batch, 512, 64);
    gemm_bf16_kernel<true, false, 4><<<MB * 4, blk, 0, stream>>>(h1, w2t2, f2b2, h2, batch, 512, 512);
    gemm_bf16_kernel<false, true, 12><<<MB * 12, blk, 0, stream>>>(h2, w3t2, f2b3, par, batch, 1536, 512);
    rqs_kernel<<<batch / 4, 256, 0, stream>>>(x, par, out, nullptr, ld1, out + (size_t)batch * DIM, 0, 2, batch);
}

// Round 5
// 342.352 us; speedup vs baseline: 1.3088x; 1.1555x over previous
//
#include <hip/hip_runtime.h>

#define DIM 128
#define HALF 64

typedef __attribute__((ext_vector_type(8))) short bf16x8;
typedef __attribute__((ext_vector_type(4))) float f32x4;

static __device__ __forceinline__ float bf2f(unsigned int u16) {
    unsigned int v = u16 << 16;
    return __builtin_bit_cast(float, v);
}
static __device__ __forceinline__ unsigned short f2bf(float f) {
    unsigned int u = __builtin_bit_cast(unsigned int, f);
    unsigned int r = 0x7fffu + ((u >> 16) & 1u);
    u += r;
    return (unsigned short)(u >> 16);
}

// async global->LDS, 16B per lane; lds dest = wave-uniform base + lane*16
static __device__ __forceinline__ void gload_lds16(const void* gptr, void* ldsptr) {
    __builtin_amdgcn_global_load_lds(
        (const __attribute__((address_space(1))) unsigned int*)(uintptr_t)gptr,
        (__attribute__((address_space(3))) unsigned int*)(unsigned int)(uintptr_t)ldsptr,
        16, 0, 0);
}

// ---------------- prep kernels ----------------

__global__ void conv_lower_kernel(const float* __restrict__ x,
                                  unsigned short* __restrict__ xl, int batch) {
    int i = blockIdx.x * 256 + threadIdx.x;
    if (i < batch * HALF) {
        int r = i >> 6, c = i & 63;
        xl[i] = f2bf(x[(size_t)r * DIM + c]);
    }
}

struct TransDesc {
    const float* src[6];
    unsigned short* dst[6];
};

// all 6 weight transposes in one launch; z selects the matrix.
// w: [K][Nin] f32 -> wt: [Npad][K] bf16 (pad24: 23->24 group pad, Npad=1536)
__global__ void transpose_all_kernel(TransDesc d) {
    __shared__ float tile[32][33];
    int z = blockIdx.z;
    int K, BN, BK, Nin, pad24;
    switch (z) {
        case 0: case 3: K = 64;  BK = 2;  BN = 16; Nin = 512;  pad24 = 0; break;
        case 1: case 4: K = 512; BK = 16; BN = 16; Nin = 512;  pad24 = 0; break;
        default:        K = 512; BK = 16; BN = 48; Nin = 1472; pad24 = 1; break;
    }
    int bn = blockIdx.x, bk = blockIdx.y;
    if (bn >= BN || bk >= BK) return;
    const float* w = d.src[z];
    unsigned short* wt = d.dst[z];
    int tx = threadIdx.x, ty = threadIdx.y;
#pragma unroll
    for (int i = 0; i < 4; ++i) {
        int k = bk * 32 + ty + 8 * i;
        int n = bn * 32 + tx;
        float v = 0.f;
        if (pad24) {
            int g = n / 24, cc = n % 24;
            if (cc < 23) v = w[(size_t)k * Nin + (g * 23 + cc)];
        } else {
            v = w[(size_t)k * Nin + n];
        }
        tile[ty + 8 * i][tx] = v;
    }
    __syncthreads();
#pragma unroll
    for (int i = 0; i < 4; ++i) {
        int n = bn * 32 + ty + 8 * i;
        int k = bk * 32 + tx;
        wt[(size_t)n * K + k] = f2bf(tile[tx][ty + 8 * i]);
    }
}

// ---------------- bf16 MFMA GEMM (m97 structure + T2 swizzle rule#21) ----------------
// C[M][N] = act(A[M][K] @ B[K][N] + bias), A bf16, Bt = B^T bf16 [N][K], C bf16.
// 128x128 tile, BK=64, 4 waves, global_load_lds(16B) staging (linear LDS dest,
// pre-swizzled GLOBAL source), XOR-swizzled ds_read -> all 32 banks hit.
// XCD chunked swizzle, N-tile fastest (A panel fetched once chip-wide).
template <bool SILU, bool PAD24, int NT>
__global__ __launch_bounds__(256, 4) void gemm_bf16_kernel(
    const unsigned short* __restrict__ A, const unsigned short* __restrict__ Bt,
    const float* __restrict__ bias, unsigned short* __restrict__ C,
    int M, int N, int K) {
    __shared__ __align__(16) unsigned char smem[34816];
    unsigned short* a_lds = (unsigned short*)smem;            // [128][64] linear
    unsigned short* b_lds = (unsigned short*)(smem + 16384);  // [128][64] linear
    unsigned short* cbuf = (unsigned short*)smem;             // epilogue, stride 136

    const int t = threadIdx.x;
    const int lane = t & 63;
    const int wid = t >> 6;
    const int wr = wid >> 1, wc = wid & 1;

    const int nwg = gridDim.x;
    const int b = blockIdx.x;
    const int id = ((nwg & 7) == 0) ? ((b & 7) * (nwg >> 3) + (b >> 3)) : b;
    const int m0 = (id / NT) * 128;
    const int n0 = (id % NT) * 128;

    const int l15 = lane & 15;
    const int l4 = lane >> 4;
    const int srow = lane >> 3;   // staging: row within 8-row chunk (0..7)
    const int sseg = lane & 7;    // staging: 16B segment within 128B row (0..7)
    const int sseg_swz = sseg ^ srow;   // pre-swizzled global segment
    const int rswz = (l15 & 7) * 8;     // ds_read elem-XOR for this lane's rows

    f32x4 acc[4][4] = {};

    for (int kt = 0; kt < K; kt += 64) {
#pragma unroll
        for (int i = 0; i < 4; ++i) {
            int chunk = wid * 4 + i;           // 8 rows per chunk
            int row = chunk * 8 + srow;
            const unsigned short* gA = A + (size_t)(m0 + row) * K + kt + sseg_swz * 8;
            const unsigned short* gB = Bt + (size_t)(n0 + row) * K + kt + sseg_swz * 8;
            gload_lds16(gA, &a_lds[chunk * 512]);
            gload_lds16(gB, &b_lds[chunk * 512]);
        }
        __syncthreads();
#pragma unroll
        for (int k0 = 0; k0 < 2; ++k0) {
            bf16x8 af[4], bfv[4];
#pragma unroll
            for (int f = 0; f < 4; ++f) {
                int col = (k0 * 32 + l4 * 8) ^ rswz;
                af[f] = *reinterpret_cast<const bf16x8*>(
                    &a_lds[(wr * 64 + f * 16 + l15) * 64 + col]);
                bfv[f] = *reinterpret_cast<const bf16x8*>(
                    &b_lds[(wc * 64 + f * 16 + l15) * 64 + col]);
            }
#pragma unroll
            for (int fm = 0; fm < 4; ++fm)
#pragma unroll
                for (int fn = 0; fn < 4; ++fn)
                    acc[fm][fn] = __builtin_amdgcn_mfma_f32_16x16x32_bf16(
                        af[fm], bfv[fn], acc[fm][fn], 0, 0, 0);
        }
        __syncthreads();
    }

    // epilogue: bias (+silu) -> bf16 tile in LDS (stride 136) -> coalesced 16B stores
    float bv[4];
#pragma unroll
    for (int fn = 0; fn < 4; ++fn) {
        int n = n0 + wc * 64 + fn * 16 + l15;
        if (PAD24) {
            int g = n / 24, cc = n % 24;
            bv[fn] = (cc < 23) ? bias[g * 23 + cc] : 0.f;
        } else {
            bv[fn] = bias[n];
        }
    }
#pragma unroll
    for (int fm = 0; fm < 4; ++fm) {
#pragma unroll
        for (int r = 0; r < 4; ++r) {
            int rl = wr * 64 + fm * 16 + l4 * 4 + r;
#pragma unroll
            for (int fn = 0; fn < 4; ++fn) {
                float v = acc[fm][fn][r] + bv[fn];
                if (SILU) v = v / (1.f + __expf(-v));
                cbuf[rl * 136 + wc * 64 + fn * 16 + l15] = f2bf(v);
            }
        }
    }
    __syncthreads();
#pragma unroll
    for (int p = 0; p < 8; ++p) {
        int unit = p * 256 + t;       // 2048 units = 128 rows x 16 segs
        int row = unit >> 4, seg = unit & 15;
        uint4 v = *reinterpret_cast<const uint4*>(&cbuf[row * 136 + seg * 8]);
        *reinterpret_cast<uint4*>(&C[(size_t)(m0 + row) * N + n0 + seg * 8]) = v;
    }
}

// ---------------- RQS spline kernel ----------------
// One wave per batch row; lane = spline dim (64 dims).
// __launch_bounds__(256,1): allow up to 256 VGPR so the unrolled knot arrays
// stay in registers (default heuristic spilled them to scratch: VGPR_Count=24,
// 69us). All transcendentals are HW-rate (__expf/__logf/v_rcp).
__global__ __launch_bounds__(256, 1) void rqs_kernel(
        const float* __restrict__ x,
        const unsigned short* __restrict__ P,  // [batch][1536]
        float* __restrict__ out, unsigned short* __restrict__ out_bf,
        float* __restrict__ ld_buf, float* __restrict__ logdet_out,
        int xoff, int pass, int batch) {
    const int wid = threadIdx.x >> 6;
    const int lane = threadIdx.x & 63;
    const int r = blockIdx.x * 4 + wid;
    if (r >= batch) return;

    const uint4* pv = reinterpret_cast<const uint4*>(P + (size_t)r * 1536 + lane * 24);
    uint4 q0 = pv[0], q1 = pv[1], q2 = pv[2];

    float W[8], H[8], Dv[7];
    {
        unsigned int a;
        a = q0.x; W[0] = bf2f(a & 0xffff); W[1] = bf2f(a >> 16);
        a = q0.y; W[2] = bf2f(a & 0xffff); W[3] = bf2f(a >> 16);
        a = q0.z; W[4] = bf2f(a & 0xffff); W[5] = bf2f(a >> 16);
        a = q0.w; W[6] = bf2f(a & 0xffff); W[7] = bf2f(a >> 16);
        a = q1.x; H[0] = bf2f(a & 0xffff); H[1] = bf2f(a >> 16);
        a = q1.y; H[2] = bf2f(a & 0xffff); H[3] = bf2f(a >> 16);
        a = q1.z; H[4] = bf2f(a & 0xffff); H[5] = bf2f(a >> 16);
        a = q1.w; H[6] = bf2f(a & 0xffff); H[7] = bf2f(a >> 16);
        a = q2.x; Dv[0] = bf2f(a & 0xffff); Dv[1] = bf2f(a >> 16);
        a = q2.y; Dv[2] = bf2f(a & 0xffff); Dv[3] = bf2f(a >> 16);
        a = q2.z; Dv[4] = bf2f(a & 0xffff); Dv[5] = bf2f(a >> 16);
        a = q2.w; Dv[6] = bf2f(a & 0xffff);
    }

    float cw[9], ch[9];
    {
        float m = W[0];
#pragma unroll
        for (int i = 1; i < 8; ++i) m = fmaxf(m, W[i]);
        float e[8], s = 0.f;
#pragma unroll
        for (int i = 0; i < 8; ++i) { e[i] = __expf(W[i] - m); s += e[i]; }
        float inv = __builtin_amdgcn_rcpf(s), cum = 0.f;
        cw[0] = -1.f;
#pragma unroll
        for (int i = 0; i < 8; ++i) {
            cum += 0.001f + 0.992f * e[i] * inv;
            cw[i + 1] = 2.f * cum - 1.f;
        }
        cw[8] = 1.f;
    }
    {
        float m = H[0];
#pragma unroll
        for (int i = 1; i < 8; ++i) m = fmaxf(m, H[i]);
        float e[8], s = 0.f;
#pragma unroll
        for (int i = 0; i < 8; ++i) { e[i] = __expf(H[i] - m); s += e[i]; }
        float inv = __builtin_amdgcn_rcpf(s), cum = 0.f;
        ch[0] = -1.f;
#pragma unroll
        for (int i = 0; i < 8; ++i) {
            cum += 0.001f + 0.992f * e[i] * inv;
            ch[i + 1] = 2.f * cum - 1.f;
        }
        ch[8] = 1.f;
    }
    float dv[9];
    dv[0] = 1.f; dv[8] = 1.f;
#pragma unroll
    for (int i = 0; i < 7; ++i) {
        float d = Dv[i];
        dv[i + 1] = 0.001f + fmaxf(d, 0.f) + __logf(1.f + __expf(-fabsf(d)));
    }

    const float xv = x[(size_t)r * DIM + xoff + lane];

    int cnt = (xv >= -1.f) ? 1 : 0;
#pragma unroll
    for (int i = 1; i < 8; ++i) cnt += (xv >= cw[i]) ? 1 : 0;
    cnt += (xv >= 1.000001f) ? 1 : 0;
    int idx = cnt - 1;
    idx = idx < 0 ? 0 : (idx > 7 ? 7 : idx);

    float in_cumw = -1.f, in_w = 1.f, in_cumh = -1.f, in_h = 1.f, d0 = 1.f, d1 = 1.f;
#pragma unroll
    for (int i = 0; i < 8; ++i) {
        bool s = (idx == i);
        float wi = cw[i + 1] - cw[i];
        float hi = ch[i + 1] - ch[i];
        in_cumw = s ? cw[i] : in_cumw;
        in_w = s ? wi : in_w;
        in_cumh = s ? ch[i] : in_cumh;
        in_h = s ? hi : in_h;
        d0 = s ? dv[i] : d0;
        d1 = s ? dv[i + 1] : d1;
    }

    float rw = __builtin_amdgcn_rcpf(in_w);
    float in_delta = in_h * rw;
    float theta = (xv - in_cumw) * rw;
    float omt = 1.f - theta;
    float t1mt = theta * omt;
    float numer = in_h * (in_delta * theta * theta + d0 * t1mt);
    float denom = in_delta + (d0 + d1 - 2.f * in_delta) * t1mt;
    float rd = __builtin_amdgcn_rcpf(denom);
    float outv = in_cumh + numer * rd;
    float dnum = in_delta * in_delta *
                 (d1 * theta * theta + 2.f * in_delta * t1mt + d0 * omt * omt);
    float lad = __logf(dnum * rd * rd);

    bool inside = (xv >= -1.f) && (xv <= 1.f);
    outv = inside ? outv : xv;
    lad = inside ? lad : 0.f;

    out[(size_t)r * DIM + xoff + lane] = outv;
    if (pass == 1) out_bf[(size_t)r * HALF + lane] = f2bf(outv);

#pragma unroll
    for (int off = 32; off > 0; off >>= 1) lad += __shfl_xor(lad, off);

    if (lane == 0) {
        if (pass == 1) ld_buf[r] = lad;
        else logdet_out[r] = lad + ld_buf[r];
    }
}

// ---------------- launcher ----------------

extern "C" void kernel_launch(void* const* d_in, const int* in_sizes, int n_in,
                              void* d_out, int out_size, void* d_ws, size_t ws_size,
                              hipStream_t stream) {
    const float* x = (const float*)d_in[0];
    const float* f1w1 = (const float*)d_in[1];
    const float* f1b1 = (const float*)d_in[2];
    const float* f1w2 = (const float*)d_in[3];
    const float* f1b2 = (const float*)d_in[4];
    const float* f1w3 = (const float*)d_in[5];
    const float* f1b3 = (const float*)d_in[6];
    const float* f2w1 = (const float*)d_in[7];
    const float* f2b1 = (const float*)d_in[8];
    const float* f2w2 = (const float*)d_in[9];
    const float* f2b2 = (const float*)d_in[10];
    const float* f2w3 = (const float*)d_in[11];
    const float* f2b3 = (const float*)d_in[12];
    const int batch = in_sizes[0] / DIM;
    float* out = (float*)d_out;

    char* ws = (char*)d_ws;
    size_t off = 0;
    auto alloc = [&](size_t bytes) -> void* {
        void* p = ws + off;
        off += (bytes + 255) & ~(size_t)255;
        return p;
    };
    unsigned short* xl = (unsigned short*)alloc((size_t)batch * 64 * 2);
    unsigned short* ub = (unsigned short*)alloc((size_t)batch * 64 * 2);
    unsigned short* w1t1 = (unsigned short*)alloc(512 * 64 * 2);
    unsigned short* w2t1 = (unsigned short*)alloc(512 * 512 * 2);
    unsigned short* w3t1 = (unsigned short*)alloc(1536 * 512 * 2);
    unsigned short* w1t2 = (unsigned short*)alloc(512 * 64 * 2);
    unsigned short* w2t2 = (unsigned short*)alloc(512 * 512 * 2);
    unsigned short* w3t2 = (unsigned short*)alloc(1536 * 512 * 2);
    unsigned short* h1 = (unsigned short*)alloc((size_t)batch * 512 * 2);
    unsigned short* h2 = (unsigned short*)alloc((size_t)batch * 512 * 2);
    unsigned short* par = (unsigned short*)alloc((size_t)batch * 1536 * 2);
    float* ld1 = (float*)alloc((size_t)batch * 4);
    (void)ws_size; (void)n_in; (void)out_size;

    // prep
    conv_lower_kernel<<<(batch * 64 + 255) / 256, 256, 0, stream>>>(x, xl, batch);
    TransDesc td;
    td.src[0] = f1w1; td.dst[0] = w1t1;
    td.src[1] = f1w2; td.dst[1] = w2t1;
    td.src[2] = f1w3; td.dst[2] = w3t1;
    td.src[3] = f2w1; td.dst[3] = w1t2;
    td.src[4] = f2w2; td.dst[4] = w2t2;
    td.src[5] = f2w3; td.dst[5] = w3t2;
    transpose_all_kernel<<<dim3(48, 16, 6), dim3(32, 8), 0, stream>>>(td);

    dim3 blk(256);
    const int MB = batch / 128;
    // pass 1: fcnn(lower) -> transform upper
    gemm_bf16_kernel<true, false, 4><<<MB * 4, blk, 0, stream>>>(xl, w1t1, f1b1, h1, batch, 512, 64);
    gemm_bf16_kernel<true, false, 4><<<MB * 4, blk, 0, stream>>>(h1, w2t1, f1b2, h2, batch, 512, 512);
    gemm_bf16_kernel<false, true, 12><<<MB * 12, blk, 0, stream>>>(h2, w3t1, f1b3, par, batch, 1536, 512);
    rqs_kernel<<<batch / 4, 256, 0, stream>>>(x, par, out, ub, ld1, nullptr, HALF, 1, batch);
    // pass 2: fcnn(upper') -> transform lower
    gemm_bf16_kernel<true, false, 4><<<MB * 4, blk, 0, stream>>>(ub, w1t2, f2b1, h1, batch, 512, 64);
    gemm_bf16_kernel<true, false, 4><<<MB * 4, blk, 0, stream>>>(h1, w2t2, f2b2, h2, batch, 512, 512);
    gemm_bf16_kernel<false, true, 12><<<MB * 12, blk, 0, stream>>>(h2, w3t2, f2b3, par, batch, 1536, 512);
    rqs_kernel<<<batch / 4, 256, 0, stream>>>(x, par, out, nullptr, ld1, out + (size_t)batch * DIM, 0, 2, batch);
}